// Round 18
// baseline (702.678 us; speedup 1.0000x reference)
//
#include <hip/hip_runtime.h>

#define B_   64
#define C_   256
#define D_   128
#define HW_  1024
#define K_   1024
#define N_   65536
#define MARGIN_PREF 1.2e-3f

typedef __attribute__((ext_vector_type(8))) short short8;
typedef __attribute__((ext_vector_type(4))) float f32x4;

__device__ __forceinline__ unsigned short f2bf(float f) {   // RNE f32->bf16
    unsigned u = __float_as_uint(f);
    return (unsigned short)((u + 0x7FFFu + ((u >> 16) & 1u)) >> 16);
}
__device__ __forceinline__ unsigned long long packdk(float d, int k) {  // order-preserving
    unsigned u = __float_as_uint(d);
    u = (u & 0x80000000u) ? ~u : (u | 0x80000000u);
    return ((unsigned long long)u << 10) | (unsigned)k;
}
__device__ __forceinline__ unsigned long long min64(unsigned long long a, unsigned long long b) {
    return a < b ? a : b;
}

// numpy pairwise-sum emulation, n=128 — scalar 8-accumulator tree (verified R4-R17)
template <typename F>
__device__ __forceinline__ float np_sum128(F ld) {
#pragma clang fp contract(off)
    float r0 = ld(0), r1 = ld(1), r2 = ld(2), r3 = ld(3);
    float r4 = ld(4), r5 = ld(5), r6 = ld(6), r7 = ld(7);
#pragma unroll
    for (int i = 8; i < 128; i += 8) {
        r0 = r0 + ld(i + 0); r1 = r1 + ld(i + 1);
        r2 = r2 + ld(i + 2); r3 = r3 + ld(i + 3);
        r4 = r4 + ld(i + 4); r5 = r5 + ld(i + 5);
        r6 = r6 + ld(i + 6); r7 = r7 + ld(i + 7);
    }
    return ((r0 + r1) + (r2 + r3)) + ((r4 + r5) + (r6 + r7));
}

// ---------------- K0: enorm (np bins) + embed -> bf16, PRE-SWIZZLED rows ----------------
__global__ __launch_bounds__(256) void k0_norms(const float* __restrict__ embed,
                                                float* __restrict__ enorm,
                                                unsigned short* __restrict__ ebf) {
#pragma clang fp contract(off)
    int k = blockIdx.x * 256 + threadIdx.x;
    if (k >= K_) return;
    const float* e = embed + (size_t)k * D_;
    enorm[k] = np_sum128([&](int i) { float v = e[i]; return v * v; });
    const int sw = (k & 7) << 4;
    char* rowp = (char*)ebf + ((size_t)k << 8);
#pragma unroll
    for (int j = 0; j < 16; ++j) {            // 16B chunks, swizzle preserves chunks
        short8 v;
#pragma unroll
        for (int q = 0; q < 8; ++q) v[q] = (short)f2bf(e[j * 8 + q]);
        *(short8*)(rowp + ((j * 16) ^ sw)) = v;
    }
}

// ---------------- K1: einsum-f32 emulation (sequential c, mul+add, no FMA) + bf16 copy ----------------
__global__ __launch_bounds__(256) void k1_proj(const float* __restrict__ z,
                                               const float* __restrict__ w,
                                               const float* __restrict__ bias,
                                               float* __restrict__ zp,
                                               unsigned short* __restrict__ zbf) {
#pragma clang fp contract(off)
    __shared__ float zs[64][64];
    __shared__ float wsh[64][128];
    const int b   = blockIdx.x >> 4;
    const int hw0 = (blockIdx.x & 15) << 6;
    const int t   = threadIdx.x;
    const int hwg = (t & 7) * 8;
    const int dg  = (t >> 3) * 4;

    float acc[8][4];
#pragma unroll
    for (int i = 0; i < 8; ++i)
#pragma unroll
        for (int j = 0; j < 4; ++j) acc[i][j] = 0.f;

    for (int ct = 0; ct < C_; ct += 64) {
        __syncthreads();
#pragma unroll
        for (int i = 0; i < 16; ++i) {
            int idx = i * 256 + t;
            int cc = idx >> 6, hwl = idx & 63;
            zs[cc][hwl] = z[(((size_t)b * C_ + ct + cc) << 10) + hw0 + hwl];
        }
#pragma unroll
        for (int i = 0; i < 32; ++i) {
            int idx = i * 256 + t;
            int cc = idx >> 7, d = idx & 127;
            wsh[cc][d] = w[(size_t)d * C_ + ct + cc];
        }
        __syncthreads();
#pragma unroll 2
        for (int cc = 0; cc < 64; ++cc) {
            float4 za = *(const float4*)&zs[cc][hwg];
            float4 zb = *(const float4*)&zs[cc][hwg + 4];
            float4 wv = *(const float4*)&wsh[cc][dg];
            float zv[8]  = {za.x, za.y, za.z, za.w, zb.x, zb.y, zb.z, zb.w};
            float wva[4] = {wv.x, wv.y, wv.z, wv.w};
#pragma unroll
            for (int i = 0; i < 8; ++i)
#pragma unroll
                for (int j = 0; j < 4; ++j) {
                    float p = zv[i] * wva[j];
                    acc[i][j] = acc[i][j] + p;
                }
        }
    }
#pragma unroll
    for (int i = 0; i < 8; ++i)
#pragma unroll
        for (int j = 0; j < 4; ++j) {
            float v = acc[i][j] + bias[dg + j];
            size_t off = (((size_t)b * HW_ + hw0 + hwg + i) << 7) + dg + j;
            zp[off]  = v;
            zbf[off] = f2bf(v);
        }
}

// ---------------- K0z: znorm[n] = np.sum(zf*zf) per row (np bins) ----------------
__global__ __launch_bounds__(256) void k0z_znorm(const float* __restrict__ zp,
                                                 float* __restrict__ znorm) {
#pragma clang fp contract(off)
    __shared__ float zl[64][129];          // +1 pad: conflict-free column reads
    const int t = threadIdx.x, n0 = blockIdx.x * 64;
#pragma unroll
    for (int i = 0; i < 32; ++i) {
        int idx = i * 256 + t;
        zl[idx >> 7][idx & 127] = zp[(size_t)n0 * 128 + idx];
    }
    __syncthreads();
    if (t < 64)
        znorm[n0 + t] = np_sum128([&](int i) { float v = zl[t][i]; return v * v; });
}

// ---------------- K2: ZERO-BARRIER MFMA prefilter + exact np-bin rescue ----------------
// k-split 4: block = 64 rows x 256 k. The 64KB e-slice is staged ONCE (async
// global_load_lds + one barrier); both passes then run barrier-free — the R9-R17
// per-iteration stage->sync->compute serialization is gone entirely.
__global__ __launch_bounds__(256) void k2_argmin(const unsigned short* __restrict__ zbf,
                                                 const unsigned short* __restrict__ ebf,
                                                 const float* __restrict__ zp,
                                                 const float* __restrict__ embed,
                                                 const float* __restrict__ enorm,
                                                 const float* __restrict__ znorm,
                                                 unsigned long long* __restrict__ pbest) {
    __shared__ unsigned char etile[65536];         // 256 k-rows x 256B (pre-swizzled)
    const int t   = threadIdx.x;
    const int l   = t & 63;
    const int wid = t >> 6;                        // 0..3
    const int rg  = blockIdx.x >> 2;               // row-group 0..1023
    const int h   = blockIdx.x & 3;                // k-quarter
    const int r0  = (rg * 4 + wid) * 16;           // wave's 16 rows
    const int kh0 = h * 256;                       // quarter's k base
    const int lr  = l & 15;
    const int lh  = l >> 4;

    // stage full 64KB slice once (async DMA, no VGPR round-trip)
    const char* src = (const char*)ebf + ((size_t)kh0 << 8);
    {
        const int lane_off = wid * 1024 + (l << 4);
#pragma unroll
        for (int i = 0; i < 16; ++i) {
            int off = i * 4096 + lane_off;
            __builtin_amdgcn_global_load_lds(
                (const __attribute__((address_space(1))) void*)(src + off),
                (__attribute__((address_space(3))) void*)(&etile[off]),
                16, 0, 0);
        }
    }

    // z fragments (B operand): 4 d-tiles (mapping verified R9-R17)
    short8 zfrag[4];
#pragma unroll
    for (int dt = 0; dt < 4; ++dt)
        zfrag[dt] = *(const short8*)(zbf + (((size_t)(r0 + lr)) << 7) + dt * 32 + lh * 8);

    // per-lane swizzled ds_read offsets (row lr, logical col dt*64+lh*16)
    const int swz = (lr & 7) << 4;
    int roff[4];
#pragma unroll
    for (int dt = 0; dt < 4; ++dt)
        roff[dt] = lr * 256 + ((dt * 64 + lh * 16) ^ swz);

    __syncthreads();                               // the ONLY barrier: drains staging

    // ---- Pass A: f32 running MIN of dist (branch-free, no k-tracking) ----
    float bmin = 1e30f;
#pragma unroll 2
    for (int st = 0; st < 8; ++st) {
#pragma unroll
        for (int ks = 0; ks < 2; ++ks) {
            const unsigned char* buf = etile + st * 8192 + ks * 4096;
            short8 af[4];
#pragma unroll
            for (int dt = 0; dt < 4; ++dt)
                af[dt] = *(const short8*)(buf + roff[dt]);
            f32x4 en4 = *(const f32x4*)(enorm + kh0 + st * 32 + ks * 16 + lh * 4);
            f32x4 acc = {0.f, 0.f, 0.f, 0.f};
#pragma unroll
            for (int dt = 0; dt < 4; ++dt)
                acc = __builtin_amdgcn_mfma_f32_16x16x32_bf16(af[dt], zfrag[dt], acc, 0, 0, 0);
#pragma unroll
            for (int reg = 0; reg < 4; ++reg)
                bmin = fminf(bmin, fmaf(-2.f, acc[reg], en4[reg]));
        }
    }
    {   // row-min across lanes {lr, lr+16, lr+32, lr+48}
        bmin = fminf(bmin, __shfl_xor(bmin, 16, 64));
        bmin = fminf(bmin, __shfl_xor(bmin, 32, 64));
    }
    const float thr = bmin + MARGIN_PREF;          // window vs TRUE quarter-row min

    // ---- Pass B: bitwise-identical recompute, collect candidates ----
    unsigned long long ca = 0, cb = 0;             // 12 x 10-bit candidate slots
    int cnt = 0;
#pragma unroll 2
    for (int st = 0; st < 8; ++st) {
#pragma unroll
        for (int ks = 0; ks < 2; ++ks) {
            const unsigned char* buf = etile + st * 8192 + ks * 4096;
            short8 af[4];
#pragma unroll
            for (int dt = 0; dt < 4; ++dt)
                af[dt] = *(const short8*)(buf + roff[dt]);
            f32x4 en4 = *(const f32x4*)(enorm + kh0 + st * 32 + ks * 16 + lh * 4);
            f32x4 acc = {0.f, 0.f, 0.f, 0.f};
#pragma unroll
            for (int dt = 0; dt < 4; ++dt)
                acc = __builtin_amdgcn_mfma_f32_16x16x32_bf16(af[dt], zfrag[dt], acc, 0, 0, 0);
#pragma unroll
            for (int reg = 0; reg < 4; ++reg) {
                float dist = fmaf(-2.f, acc[reg], en4[reg]);
                if (dist < thr) {
                    int kk = kh0 + st * 32 + ks * 16 + lh * 4 + reg;
                    if (cnt < 6)       ca |= (unsigned long long)kk << (10 * cnt);
                    else if (cnt < 12) cb |= (unsigned long long)kk << (10 * (cnt - 6));
                    ++cnt;
                }
            }
        }
    }

    // ---- Phase C: exact np-bin refine of candidates (R4-verified chain) ----
    const int myrow = r0 + lr;
    const float* zrow = zp + ((size_t)myrow << 7);
    const float  zn   = znorm[myrow];
    unsigned long long best = ~0ull;

    auto refine = [&](int kk) {
#pragma clang fp contract(off)
        const float* e = embed + ((size_t)kk << 7);
        float s = 0.f;
#pragma unroll 1
        for (int d = 0; d < 128; ++d) s = fmaf(zrow[d], e[d], s);
        float T  = 2.0f * s;
        float A  = zn - T;                  // bin-maker 1 (mag ~13)
        float Bv = A + enorm[kk];           // bin-maker 2
        best = min64(best, packdk(Bv, kk)); // lex (bin, k) = np first-occurrence
    };

    if (cnt <= 12) {
#pragma unroll
        for (int i = 0; i < 6; ++i)
            if (i < cnt) refine((int)((ca >> (10 * i)) & 1023ull));
#pragma unroll
        for (int i = 6; i < 12; ++i)
            if (i < cnt) refine((int)((cb >> (10 * (i - 6))) & 1023ull));
    } else {                                // overflow fallback: lane's k-subset in quarter
#pragma unroll 1
        for (int st = 0; st < 8; ++st)
#pragma unroll
            for (int ks = 0; ks < 2; ++ks)
#pragma unroll
                for (int reg = 0; reg < 4; ++reg)
                    refine(kh0 + st * 32 + ks * 16 + lh * 4 + reg);
    }
    {   // row-min across lanes {lr, lr+16, lr+32, lr+48}
        unsigned long long o;
        o = __shfl_xor(best, 16, 64); best = min64(best, o);
        o = __shfl_xor(best, 32, 64); best = min64(best, o);
    }
    if (l < 16)
        pbest[((size_t)(r0 + l) << 2) + h] = best;
}

// ---------------- K3: combine quarters + gather + NCHW transpose + indices ----------------
__global__ __launch_bounds__(256) void k3_gather(const float* __restrict__ embed,
                                                 const unsigned long long* __restrict__ pbest,
                                                 float* __restrict__ out0,
                                                 float* __restrict__ out_idx) {
    __shared__ float tile[64][129];
    __shared__ int   kks[64];
    const int b   = blockIdx.x >> 4;
    const int hw0 = (blockIdx.x & 15) << 6;
    const int t   = threadIdx.x;
    const int n0  = b * HW_ + hw0;
    if (t < 64) {
        int row = n0 + t;
        const unsigned long long* p = pbest + ((size_t)row << 2);
        unsigned long long m = min64(min64(p[0], p[1]), min64(p[2], p[3]));
        int kk = (int)(m & 1023ull);
        kks[t] = kk;
        out_idx[row] = (float)kk;
    }
    __syncthreads();
#pragma unroll
    for (int i = 0; i < 32; ++i) {
        int idx = i * 256 + t;
        int hwl = idx >> 7, d = idx & 127;
        tile[hwl][d] = embed[(size_t)kks[hwl] * 128 + d];
    }
    __syncthreads();
#pragma unroll
    for (int i = 0; i < 32; ++i) {
        int idx = i * 256 + t;
        int d = idx >> 6, hwl = idx & 63;
        out0[(((size_t)b * D_ + d) << 10) + hw0 + hwl] = tile[hwl][d];
    }
}

extern "C" void kernel_launch(void* const* d_in, const int* in_sizes, int n_in,
                              void* d_out, int out_size, void* d_ws, size_t ws_size,
                              hipStream_t stream) {
    const float* z     = (const float*)d_in[0];
    const float* pw    = (const float*)d_in[1];
    const float* pb    = (const float*)d_in[2];
    const float* embed = (const float*)d_in[3];

    float* out0 = (float*)d_out;
    float* out1 = (float*)d_out + (size_t)B_ * D_ * HW_;

    char* ws = (char*)d_ws;
    float*              zp    = (float*)ws;                                 // 32 MB
    unsigned short*     zbf   = (unsigned short*)(ws + (32u << 20));        // 16 MB
    unsigned short*     ebf   = (unsigned short*)(ws + (48u << 20));        // 256 KB
    float*              enorm = (float*)(ws + (48u << 20) + (256u << 10));  // 4 KB
    float*              znorm = (float*)(ws + (49u << 20));                 // 256 KB
    unsigned long long* pbest = (unsigned long long*)(ws + (50u << 20));    // 2 MB

    hipLaunchKernelGGL(k0_norms,  dim3(4),    dim3(256), 0, stream, embed, enorm, ebf);
    hipLaunchKernelGGL(k1_proj,   dim3(1024), dim3(256), 0, stream, z, pw, pb, zp, zbf);
    hipLaunchKernelGGL(k0z_znorm, dim3(1024), dim3(256), 0, stream, zp, znorm);
    hipLaunchKernelGGL(k2_argmin, dim3(4096), dim3(256), 0, stream,
                       zbf, ebf, zp, embed, enorm, znorm, pbest);
    hipLaunchKernelGGL(k3_gather, dim3(1024), dim3(256), 0, stream, embed, pbest, out0, out1);
}